// Round 15
// baseline (63.434 us; speedup 1.0000x reference)
//
#include <hip/hip_runtime.h>

#define NMOL   32
#define NATOM  512
#define NPAIR  32768
#define NB     64
#define HIDDEN 256
#define TOTNATOM (NMOL * NATOM)
#define NSUB   8
#define CAP8   16    // records per (atom, sub-block)
#define ABLK   16    // atoms per gnn2 block
#define SLOTS  128   // LDS record slots per atom

typedef __attribute__((ext_vector_type(8))) short bf16x8;
typedef __attribute__((ext_vector_type(4))) float f32x4;

__device__ __forceinline__ unsigned short f2bf(float x) {   // RNE f32->bf16
    unsigned u = __float_as_uint(x);
    u += 0x7FFFu + ((u >> 16) & 1u);
    return (unsigned short)(u >> 16);
}

// ---------------------------------------------------------------------------
// K1 scatter: unchanged structure (R12-R14). 256 blocks x 1024 thr;
// LDS-private counters, per-block record segments, zero cross-XCD atomics.
// Block 0 additionally zeroes dipole (stream order covers gnn2's atomics).
// ---------------------------------------------------------------------------
__global__ __launch_bounds__(1024) void scatter_kernel(
    const float* __restrict__ cart, const float* __restrict__ shifts,
    const int* __restrict__ species, const int* __restrict__ atom_index,
    unsigned* __restrict__ cnt8, float2* __restrict__ rec,
    float* __restrict__ tv_part, float* __restrict__ dipole, int ndip)
{
    __shared__ float    tv_sc[NATOM * 3];   // 6 KB
    __shared__ float    s_cart[NATOM * 3];  // 6 KB
    __shared__ int      s_sp[NATOM];        // 2 KB
    __shared__ unsigned lcnt[NATOM];        // 2 KB
    const int tid = threadIdx.x;
    const int b   = blockIdx.x;
    const int mol = b >> 3;
    const int sub = b & 7;

    if (b == 0 && tid < ndip) dipole[tid] = 0.f;

    const float* cm = cart + (size_t)mol * NATOM * 3;
    const int*   sp = species + (size_t)mol * NATOM;
    for (int i = tid; i < NATOM * 3; i += 1024) { tv_sc[i] = 0.f; s_cart[i] = cm[i]; }
    if (tid < NATOM) { lcnt[tid] = 0u; s_sp[tid] = sp[tid]; }
    __syncthreads();

    const int* ai0 = atom_index + (size_t)mol * NPAIR;
    const int* ai1 = ai0 + (size_t)NMOL * NPAIR;
    const float* sh = shifts + (size_t)mol * NPAIR * 3;
    const int base = sub * 4096;

#pragma unroll
    for (int k = 0; k < 4; ++k) {
        const int p  = base + k * 1024 + tid;
        const int i0 = ai0[p];
        const int i1 = ai1[p];
        const float sx = sh[p * 3 + 0], sy = sh[p * 3 + 1], sz = sh[p * 3 + 2];
        if (!(sx > -1e10f && sy > -1e10f && sz > -1e10f)) continue;  // masked
        const float dx = s_cart[i0 * 3 + 0] - s_cart[i1 * 3 + 0] + sx;
        const float dy = s_cart[i0 * 3 + 1] - s_cart[i1 * 3 + 1] + sy;
        const float dz = s_cart[i0 * 3 + 2] - s_cart[i1 * 3 + 2] + sz;
        unsafeAtomicAdd(&tv_sc[i0 * 3 + 0], dx);        // ds_add_f32
        unsafeAtomicAdd(&tv_sc[i0 * 3 + 1], dy);
        unsafeAtomicAdd(&tv_sc[i0 * 3 + 2], dz);
        const float d = sqrtf(dx * dx + dy * dy + dz * dz + 1e-12f);
        if (d < 5.0f) {
            const float fc = 0.5f * (__cosf(0.62831853071795864769f * d) + 1.f);
            // pack spc into fc's low 3 mantissa bits (<=2^-20 rel perturbation)
            const unsigned fb = (__float_as_uint(fc) & ~7u) | (unsigned)s_sp[i1];
            const unsigned pos = atomicAdd(&lcnt[i0], 1u);   // LDS, native
            if (pos < CAP8)
                rec[((size_t)b * NATOM + i0) * CAP8 + pos] =
                    make_float2(d, __uint_as_float(fb));
        }
    }
    __syncthreads();

    if (tid < NATOM) cnt8[((size_t)mol * NATOM + tid) * NSUB + sub] = lcnt[tid];
    float* tg = tv_part + (size_t)b * NATOM * 3;
    for (int i = tid; i < NATOM * 3; i += 1024) tg[i] = tv_sc[i];
}

// ---------------------------------------------------------------------------
// K2 gnn2: gather + MFMA-nn fused. 1024 blocks x 256 thr, 16 atoms/block.
// SAFE TO FUSE NOW: both phases are ~40-50 VGPR with no large per-thread
// arrays (the w1r[64] that poisoned R8/R12/R13 fusions is gone -- weights
// live in LDS as MFMA B-fragments). Density: LDS bf16 rows, never leaves CU.
//   phase A: stage W1^T(bf16, pad 72) + cemb + counts; prefix; segment copy
//   phase B: gather (wave = 4 atoms, lane = basis) -> dens_bf LDS
//   phase C: all 4 waves on the same 16-atom M-tile, wave = 4 N-tiles (64 j)
//            2x mfma_f32_16x16x32_bf16 per N-tile; silu*W2; fr-shuffle and
//            cross-wave reduce; 3 dipole atomics/block (3K total, harmless)
// ---------------------------------------------------------------------------
__global__ __launch_bounds__(256) void gnn2_kernel(
    const unsigned* __restrict__ cnt8, const float2* __restrict__ rec,
    const float* __restrict__ centers, const float* __restrict__ widths,
    const float* __restrict__ c_emb, const float* __restrict__ tv_part,
    const float* __restrict__ W1, const float* __restrict__ b1,
    const float* __restrict__ W2, const float* __restrict__ b2,
    float* __restrict__ dipole)
{
    __shared__ float    cemb[8 * NB];                       // 2 KB
    __shared__ float2   list[ABLK][SLOTS];                  // 16 KB
    __shared__ unsigned scnt[ABLK][NSUB];
    __shared__ unsigned soff[ABLK][NSUB];
    __shared__ unsigned mtot[ABLK];
    __shared__ __align__(16) unsigned short w1t[HIDDEN * 72];   // 36 KB
    __shared__ __align__(16) unsigned short dens_bf[ABLK][72];  // 2.25 KB
    __shared__ float    b1_l[HIDDEN], w2_l[HIDDEN];         // 2 KB
    __shared__ float    tv_l[ABLK * 3];
    __shared__ float    sred[4][4][4];                      // [wave][fg][i]

    const int tid = threadIdx.x;
    const int a0  = blockIdx.x * ABLK;
    const int mol = a0 >> 9;
    const int ra0 = a0 & 511;

    // ---- phase A: stage everything ----
    for (int i = tid; i < 8 * NB; i += 256) cemb[i] = c_emb[i];
    for (int i = tid; i < NB * HIDDEN; i += 256) {      // W1^T as bf16, pad 72
        const int k = i >> 8, j = i & 255;              // coalesced f32 reads
        w1t[j * 72 + k] = f2bf(W1[i]);
    }
    if (tid < HIDDEN) { b1_l[tid] = b1[tid]; w2_l[tid] = W2[tid]; }
    if (tid < ABLK * NSUB) {
        const int al = tid >> 3, s = tid & 7;
        scnt[al][s] = cnt8[(size_t)(a0 + al) * NSUB + s];
    }
    if (tid < ABLK * 3) {                               // tv partial sums
        const int al = tid / 3, c = tid - al * 3;
        float s = 0.f;
#pragma unroll
        for (int sb = 0; sb < NSUB; ++sb)
            s += tv_part[((size_t)(mol * NSUB + sb) * NATOM + (ra0 + al)) * 3 + c];
        tv_l[al * 3 + c] = s;
    }
    __syncthreads();

    if (tid < ABLK) {    // per-atom prefix over 8 segment counts + zero-pad
        unsigned o = 0;
#pragma unroll
        for (int s = 0; s < NSUB; ++s) {
            soff[tid][s] = o;
            o += min(scnt[tid][s], (unsigned)CAP8);
        }
        const unsigned mp = (o + 7u) & ~7u;             // pad to multiple of 8
        mtot[tid] = mp;
        for (unsigned k = o; k < mp; ++k) list[tid][k] = make_float2(0.f, 0.f);
    }
    __syncthreads();

    {   // parallel segment copy: 2 threads per (atom, sub) segment
        const int seg = tid >> 1;                       // 0..127
        const int prt = tid & 1;
        const int al = seg >> 3, s = seg & 7;
        const int n = (int)min(scnt[al][s], (unsigned)CAP8);
        const float2* src = rec + ((size_t)(mol * NSUB + s) * NATOM + (ra0 + al)) * CAP8;
        float2* dst = &list[al][soff[al][s]];
        const int k0 = prt * 8, k1 = min(k0 + 8, n);
        for (int k = k0; k < k1; ++k) dst[k] = src[k];
    }
    __syncthreads();

    const int lane = tid & 63;
    const int wave = tid >> 6;

    // ---- phase B: gather (wave = 4 atoms, lane = basis) ----
    {
        const float cb   = centers[lane];
        const float nwb2 = -widths[lane] * 1.4426950408889634f;  // fold log2(e)

#define REC1(A, dv, fv) { const unsigned f_ = __float_as_uint(fv);           \
        const float t_ = (dv) - cb;                                          \
        A = fmaf(exp2f(nwb2 * t_ * t_) * __uint_as_float(f_ & ~7u),          \
                 cemb[((f_ & 7u) << 6) | lane], A); }

        for (int al = wave; al < ABLK; al += 4) {
            const int m = (int)mtot[al];
            const float4* l4 = reinterpret_cast<const float4*>(list[al]);
            float acc0 = 0.f, acc1 = 0.f;
            for (int j = 0; j < m; j += 8) {
                const float4 q0 = l4[(j >> 1) + 0];
                const float4 q1 = l4[(j >> 1) + 1];
                const float4 q2 = l4[(j >> 1) + 2];
                const float4 q3 = l4[(j >> 1) + 3];
                REC1(acc0, q0.x, q0.y) REC1(acc1, q0.z, q0.w)
                REC1(acc0, q1.x, q1.y) REC1(acc1, q1.z, q1.w)
                REC1(acc0, q2.x, q2.y) REC1(acc1, q2.z, q2.w)
                REC1(acc0, q3.x, q3.y) REC1(acc1, q3.z, q3.w)
            }
            dens_bf[al][lane] = f2bf(acc0 + acc1);      // 2 lanes/bank: free
        }
#undef REC1
    }
    __syncthreads();

    // ---- phase C: MFMA nn. All waves share the 16-atom M-tile; wave w
    //      covers N-tiles nt = 4w..4w+3 (64 j's). ----
    {
        const int fr = lane & 15;      // C col (j within tile) / A-B row
        const int fg = lane >> 4;      // k-group; C rows = fg*4+i

        bf16x8 afr[2];
#pragma unroll
        for (int kk = 0; kk < 2; ++kk)
            afr[kk] = *reinterpret_cast<const bf16x8*>(
                &dens_bf[fr][kk * 32 + fg * 8]);

        float sdip[4] = {0.f, 0.f, 0.f, 0.f};
#pragma unroll
        for (int t = 0; t < 4; ++t) {
            const int nt = wave * 4 + t;
            const bf16x8 bf0 = *reinterpret_cast<const bf16x8*>(
                &w1t[(nt * 16 + fr) * 72 + 0 + fg * 8]);
            const bf16x8 bf1 = *reinterpret_cast<const bf16x8*>(
                &w1t[(nt * 16 + fr) * 72 + 32 + fg * 8]);
            f32x4 acc = {0.f, 0.f, 0.f, 0.f};
            acc = __builtin_amdgcn_mfma_f32_16x16x32_bf16(afr[0], bf0, acc, 0, 0, 0);
            acc = __builtin_amdgcn_mfma_f32_16x16x32_bf16(afr[1], bf1, acc, 0, 0, 0);
            const int j = nt * 16 + fr;
            const float b1v = b1_l[j], w2v = w2_l[j];
#pragma unroll
            for (int i = 0; i < 4; ++i) {               // silu * W2
                const float h = acc[i] + b1v;
                sdip[i] += (h / (1.f + __expf(-h))) * w2v;
            }
        }
#pragma unroll
        for (int off = 1; off < 16; off <<= 1) {        // reduce over 16 j-cols
#pragma unroll
            for (int i = 0; i < 4; ++i) sdip[i] += __shfl_xor(sdip[i], off);
        }
        if (fr == 0) {
#pragma unroll
            for (int i = 0; i < 4; ++i) sred[wave][fg][i] = sdip[i];
        }
        __syncthreads();

        if (tid < ABLK) {                               // atom a = tid
            const int a = tid;
            const float out = sred[0][a >> 2][a & 3] + sred[1][a >> 2][a & 3]
                            + sred[2][a >> 2][a & 3] + sred[3][a >> 2][a & 3]
                            + b2[0];
            float px = out * tv_l[a * 3 + 0];
            float py = out * tv_l[a * 3 + 1];
            float pz = out * tv_l[a * 3 + 2];
#pragma unroll
            for (int off = 8; off; off >>= 1) {
                px += __shfl_down(px, off, 16);
                py += __shfl_down(py, off, 16);
                pz += __shfl_down(pz, off, 16);
            }
            if (a == 0) {
                unsafeAtomicAdd(&dipole[mol * 3 + 0], px);
                unsafeAtomicAdd(&dipole[mol * 3 + 1], py);
                unsafeAtomicAdd(&dipole[mol * 3 + 2], pz);
            }
        }
    }
}

// ---------------------------------------------------------------------------
extern "C" void kernel_launch(void* const* d_in, const int* in_sizes, int n_in,
                              void* d_out, int out_size, void* d_ws, size_t ws_size,
                              hipStream_t stream)
{
    const float* cart       = (const float*)d_in[0];
    const float* shifts     = (const float*)d_in[1];
    const float* centers    = (const float*)d_in[2];
    const float* widths     = (const float*)d_in[3];
    const float* c_emb      = (const float*)d_in[4];
    const float* W1         = (const float*)d_in[5];
    const float* b1         = (const float*)d_in[6];
    const float* W2         = (const float*)d_in[7];
    const float* b2         = (const float*)d_in[8];
    const int*   species    = (const int*)d_in[10];
    const int*   atom_index = (const int*)d_in[11];

    // ws: tv_part(1.5MB) | cnt8(512KB) | rec(16MB)
    float*    tv_part = (float*)d_ws;
    unsigned* cnt8    = (unsigned*)(tv_part + (size_t)NMOL * NSUB * NATOM * 3);
    float2*   rec     = (float2*)(cnt8 + (size_t)TOTNATOM * NSUB);
    float*    dipole  = (float*)d_out;

    hipLaunchKernelGGL(scatter_kernel, dim3(NMOL * NSUB), dim3(1024), 0, stream,
                       cart, shifts, species, atom_index, cnt8, rec, tv_part,
                       dipole, out_size);
    hipLaunchKernelGGL(gnn2_kernel, dim3(TOTNATOM / ABLK), dim3(256), 0, stream,
                       cnt8, rec, centers, widths, c_emb, tv_part,
                       W1, b1, W2, b2, dipole);
}